// Round 1
// baseline (87.552 us; speedup 1.0000x reference)
//
#include <hip/hip_runtime.h>

#define BB    32
#define CINc  64
#define HHc   32
#define WWc   32
#define COc   64
#define KSc   7
#define GGc   8
#define PADc  3
#define CPGc  8
#define NPIX  (HHc * WWc)      // 1024

typedef _Float16 h8    __attribute__((ext_vector_type(8)));
typedef _Float16 h2    __attribute__((ext_vector_type(2)));
typedef float    f32x4 __attribute__((ext_vector_type(4)));

#if defined(__has_builtin)
#if __has_builtin(__builtin_amdgcn_fdot2)
#define HAVE_FDOT2 1
#endif
#endif

// Round 15: tap-phase DS cut via vertical pixel pairing.
// Projection (16 waves, MFMA) unchanged. After the barrier, waves 8..15
// retire; waves 0..7 each own rows (2h', 2h'+1) at one column and read the
// shared 8-row x 7-col k/v window ONCE: 112 ds_read_b128 per 2 px (56/px
// vs 98/px) -> tap DS wave-insts 1568 -> 896 per CU (-43%). Lane->addr
// pattern identical to the old conflict-free one (32 consecutive 16B
// chunks per half-wave, row stride 512B = 2-way alias = free).
// Accumulation order per pixel is bit-identical (ki outer, kj inner).
// Prior structural notes (rounds <=14) still apply:
//  - live set must stay under the 128-VGPR 4-waves/SIMD cap (>=8 w/SIMD spills).
//  - XCD swizzle (image's 8 group-blocks on one XCD) keeps FETCH ~4.5 MB.
__global__ __launch_bounds__(1024, 4) void fused_kernel(
    const float* __restrict__ x,      // [B][64][32][32]
    const float* __restrict__ wq,     // [64][64]
    const float* __restrict__ wk,
    const float* __restrict__ wv,
    const float* __restrict__ rel_h,  // [32][7]
    const float* __restrict__ rel_w,  // [32][7]
    const float* __restrict__ cv,     // [8]
    float* __restrict__ out)          // [B][64][32][32]
{
    __shared__ __attribute__((aligned(16))) f32x4 kplv[NPIX];  // k[0:8] f16  16KB
    __shared__ __attribute__((aligned(16))) f32x4 vplv[NPIX];  // v[0:8] f16  16KB
    __shared__ __attribute__((aligned(16))) f32x4 qplv[NPIX];  // q[0:8] f16  16KB

    const int bi  = blockIdx.x;
    const int xcd = bi & 7;            // XCD swizzle (image's 8 groups share L2)
    const int t   = bi >> 3;
    const int im  = t & 3;
    const int g   = t >> 2;
    const int b   = im * 8 + xcd;
    const int o0  = g * CPGc;
    const int tid = threadIdx.x;       // = pixel index 0..1023 (projection phase)

    const int lane = tid & 63;
    const int wp   = (tid >> 6) << 6;  // wave's 64-pixel base
    const int an   = lane & 15;        // A m-index / B,D n-index
    const int quad = lane >> 4;

    const float* xb = x + (size_t)b * CINc * NPIX;

    // ---------- B fragments (weights, f32 -> f16) ----------
    // N-tile0: n<8 -> k channel n, n>=8 -> v channel n-8.  N-tile1: q (n>=8 pad).
    h8 bf[2][2];
    {
        const float* br0 = (an < 8) ? (wk + (o0 + an) * CINc)
                                    : (wv + (o0 + an - 8) * CINc);
        const float* br1 = wq + (o0 + ((an < 8) ? an : 0)) * CINc;
#pragma unroll
        for (int ks = 0; ks < 2; ++ks) {
            const int c0 = ks * 32 + quad * 8;
#pragma unroll
            for (int jj = 0; jj < 8; ++jj) {
                bf[0][ks][jj] = (_Float16)br0[c0 + jj];
                bf[1][ks][jj] = (_Float16)br1[c0 + jj];
            }
        }
    }

    // ---------- MFMA projection: 4 M-tiles x 2 N-tiles, K=64 in 2 steps ----------
    f32x4 acc0[4], acc1[4];
#pragma unroll
    for (int m = 0; m < 4; ++m) { acc0[m] = (f32x4)0.f; acc1[m] = (f32x4)0.f; }

#pragma unroll
    for (int m = 0; m < 4; ++m) {
        const float* xpx = xb + wp + m * 16 + an;   // this lane's pixel column
#pragma unroll
        for (int ks = 0; ks < 2; ++ks) {
            const int c0 = ks * 32 + quad * 8;
            h8 a;
#pragma unroll
            for (int jj = 0; jj < 8; ++jj)
                a[jj] = (_Float16)xpx[(c0 + jj) * NPIX];
            acc0[m] = __builtin_amdgcn_mfma_f32_16x16x32_f16(a, bf[0][ks], acc0[m], 0, 0, 0);
            acc1[m] = __builtin_amdgcn_mfma_f32_16x16x32_f16(a, bf[1][ks], acc1[m], 0, 0, 0);
        }
    }

    // ---------- scatter D -> LDS planes (C-layout: pix = quad*4+reg) ----------
    {
        _Float16* kp16 = (_Float16*)kplv;
        _Float16* qp16 = (_Float16*)qplv;
        _Float16* vp16 = (_Float16*)vplv;
#pragma unroll
        for (int m = 0; m < 4; ++m) {
#pragma unroll
            for (int r = 0; r < 4; ++r) {
                const int pix = wp + m * 16 + quad * 4 + r;
                const float d0 = acc0[m][r];
                if (an < 8) {
                    kp16[pix * 8 + an] = (_Float16)d0;
                    qp16[pix * 8 + an] = (_Float16)acc1[m][r];
                } else {
                    vp16[pix * 8 + (an - 8)] = (_Float16)d0;
                }
            }
        }
    }

    __syncthreads();

    // ---------- tap phase: waves 8..15 retire; waves 0..7 take a row pair ----------
    if (tid >= 512) return;

    const int w  = tid & 31;           // column
    const int hp = tid >> 5;           // row-pair index 0..15
    const int h0 = hp << 1;            // even row
    const int h1 = h0 | 1;             // odd row

    // ---------- own-pixel q for both rows ----------
    f32x4 qraw0 = qplv[(h0 << 5) + w];
    f32x4 qraw1 = qplv[(h1 << 5) + w];
    const h2* qh0p = (const h2*)&qraw0;
    const h2* qh1p = (const h2*)&qraw1;
    h2 q20[4] = {qh0p[0], qh0p[1], qh0p[2], qh0p[3]};
    h2 q21[4] = {qh1p[0], qh1p[1], qh1p[2], qh1p[3]};
    float qf0[CPGc], qf1[CPGc];
#pragma unroll
    for (int jj = 0; jj < 4; ++jj) {
        qf0[2 * jj]     = (float)q20[jj].x;
        qf0[2 * jj + 1] = (float)q20[jj].y;
        qf1[2 * jj]     = (float)q21[jj].x;
        qf1[2 * jj + 1] = (float)q21[jj].y;
    }

    // qrel[t] = sum_oi q[oi] * rel[oi][t], for both pixels
    const bool use_h = (g < 4);
    const float* relp = use_h ? (rel_h + o0 * KSc) : (rel_w + (o0 - 32) * KSc);
    float qrel0[KSc], qrel1[KSc];
#pragma unroll
    for (int tt = 0; tt < KSc; ++tt) {
        float s0 = 0.f, s1 = 0.f;
#pragma unroll
        for (int oi = 0; oi < CPGc; ++oi) {
            const float rv = relp[oi * KSc + tt];
            s0 = fmaf(qf0[oi], rv, s0);
            s1 = fmaf(qf1[oi], rv, s1);
        }
        qrel0[tt] = s0;
        qrel1[tt] = s1;
    }

    // per-kj clamped col + in-bounds mask (shared by both pixels: same column)
    int  xcl[KSc];
    bool xin[KSc];
#pragma unroll
    for (int kj = 0; kj < KSc; ++kj) {
        const int xx = w + kj - PADc;
        xin[kj] = (xx >= 0) && (xx < WWc);
        xcl[kj] = min(max(xx, 0), WWc - 1);
    }

    // ---------- shared 8-row window: each (row,col) k/v read ONCE ----------
    float den0 = 0.f, den1 = 0.f;
    float a0[CPGc], a1[CPGc];
#pragma unroll
    for (int oi = 0; oi < CPGc; ++oi) { a0[oi] = 0.f; a1[oi] = 0.f; }

#pragma unroll
    for (int p = 0; p < KSc + 1; ++p) {    // absolute row y = h0 + p - PAD
        const int y    = h0 + p - PADc;    // px0: ki = p (p<7); px1: ki = p-1 (p>0)
        const bool yin = (y >= 0) && (y < HHc);
        const int base = min(max(y, 0), HHc - 1) * WWc;
#pragma unroll
        for (int kj = 0; kj < KSc; ++kj) {
            const int pos = base + xcl[kj];
            const f32x4 kraw = kplv[pos];
            const f32x4 vraw = vplv[pos];
            const bool in = yin && xin[kj];
            const h2* kh = (const h2*)&kraw;
            const h2* vh = (const h2*)&vraw;

            if (p < KSc) {                 // pixel (h0, w), ki = p
                float d = 0.f;
#if HAVE_FDOT2
                d = __builtin_amdgcn_fdot2(q20[0], kh[0], d, false);
                d = __builtin_amdgcn_fdot2(q20[1], kh[1], d, false);
                d = __builtin_amdgcn_fdot2(q20[2], kh[2], d, false);
                d = __builtin_amdgcn_fdot2(q20[3], kh[3], d, false);
#else
#pragma unroll
                for (int jj = 0; jj < 4; ++jj) {
                    d = fmaf(qf0[2 * jj],     (float)kh[jj].x, d);
                    d = fmaf(qf0[2 * jj + 1], (float)kh[jj].y, d);
                }
#endif
                const float s = (use_h ? qrel0[p] : qrel0[kj]) + (in ? d : 0.f);
                const float e = __expf(s);      // OOB: e = exp(qrel) (ref zero-pad)
                den0 += e;
                const float ev = in ? e : 0.f;
                a0[0] = fmaf(ev, (float)vh[0].x, a0[0]);
                a0[1] = fmaf(ev, (float)vh[0].y, a0[1]);
                a0[2] = fmaf(ev, (float)vh[1].x, a0[2]);
                a0[3] = fmaf(ev, (float)vh[1].y, a0[3]);
                a0[4] = fmaf(ev, (float)vh[2].x, a0[4]);
                a0[5] = fmaf(ev, (float)vh[2].y, a0[5]);
                a0[6] = fmaf(ev, (float)vh[3].x, a0[6]);
                a0[7] = fmaf(ev, (float)vh[3].y, a0[7]);
            }
            if (p > 0) {                   // pixel (h1, w), ki = p-1
                float d = 0.f;
#if HAVE_FDOT2
                d = __builtin_amdgcn_fdot2(q21[0], kh[0], d, false);
                d = __builtin_amdgcn_fdot2(q21[1], kh[1], d, false);
                d = __builtin_amdgcn_fdot2(q21[2], kh[2], d, false);
                d = __builtin_amdgcn_fdot2(q21[3], kh[3], d, false);
#else
#pragma unroll
                for (int jj = 0; jj < 4; ++jj) {
                    d = fmaf(qf1[2 * jj],     (float)kh[jj].x, d);
                    d = fmaf(qf1[2 * jj + 1], (float)kh[jj].y, d);
                }
#endif
                const float s = (use_h ? qrel1[p - 1] : qrel1[kj]) + (in ? d : 0.f);
                const float e = __expf(s);
                den1 += e;
                const float ev = in ? e : 0.f;
                a1[0] = fmaf(ev, (float)vh[0].x, a1[0]);
                a1[1] = fmaf(ev, (float)vh[0].y, a1[1]);
                a1[2] = fmaf(ev, (float)vh[1].x, a1[2]);
                a1[3] = fmaf(ev, (float)vh[1].y, a1[3]);
                a1[4] = fmaf(ev, (float)vh[2].x, a1[4]);
                a1[5] = fmaf(ev, (float)vh[2].y, a1[5]);
                a1[6] = fmaf(ev, (float)vh[3].x, a1[6]);
                a1[7] = fmaf(ev, (float)vh[3].y, a1[7]);
            }
        }
    }

    // ---------- adaptive mask + write (both pixels) ----------
    const float cvg = cv[g];
    float* ob = out + ((size_t)b * COc + o0) * NPIX;

    {
        const int  r  = min(h0, HHc - 1 - h0);
        const int  lo = (h0 <= HHc - 1 - h0) ? r : r + 1;
        const int  hi = HHc - 1 - r;
        const bool in_ring = (w >= lo) && (w <= hi);
        float om = ((float)r - 15.0f + cvg * 16.0f) * (1.0f / 3.0f) + 1.0f;
        om = fminf(fmaxf(om, 0.0f), 1.0f);
        const float maskv = in_ring ? om : 1.0f;
        const float scale = maskv / den0;
        const int   px = (h0 << 5) + w;
#pragma unroll
        for (int oi = 0; oi < CPGc; ++oi)
            ob[(size_t)oi * NPIX + px] = a0[oi] * scale;
    }
    {
        const int  r  = min(h1, HHc - 1 - h1);
        const int  lo = (h1 <= HHc - 1 - h1) ? r : r + 1;
        const int  hi = HHc - 1 - r;
        const bool in_ring = (w >= lo) && (w <= hi);
        float om = ((float)r - 15.0f + cvg * 16.0f) * (1.0f / 3.0f) + 1.0f;
        om = fminf(fmaxf(om, 0.0f), 1.0f);
        const float maskv = in_ring ? om : 1.0f;
        const float scale = maskv / den1;
        const int   px = (h1 << 5) + w;
#pragma unroll
        for (int oi = 0; oi < CPGc; ++oi)
            ob[(size_t)oi * NPIX + px] = a1[oi] * scale;
    }
}

extern "C" void kernel_launch(void* const* d_in, const int* in_sizes, int n_in,
                              void* d_out, int out_size, void* d_ws, size_t ws_size,
                              hipStream_t stream) {
    const float* x     = (const float*)d_in[0];
    const float* wq    = (const float*)d_in[1];
    const float* wk    = (const float*)d_in[2];
    const float* wv    = (const float*)d_in[3];
    const float* rel_h = (const float*)d_in[4];
    const float* rel_w = (const float*)d_in[5];
    const float* cv    = (const float*)d_in[6];
    float* out = (float*)d_out;

    fused_kernel<<<256, 1024, 0, stream>>>(x, wq, wk, wv, rel_h, rel_w, cv, out);
}